// Round 3
// baseline (919.440 us; speedup 1.0000x reference)
//
#include <hip/hip_runtime.h>
#include <hip/hip_bf16.h>
#include <cstdint>
#include <math.h>

// Problem constants (from reference)
#define T_TOK 4096
#define E_EXP 64
#define KSEL  8
#define H_DIM 1024
#define F_DIM 512
#define C_CAP 1024

typedef __bf16 bf16x8 __attribute__((ext_vector_type(8)));
typedef __bf16 bf16x4 __attribute__((ext_vector_type(4)));
typedef float  f32x4  __attribute__((ext_vector_type(4)));

// ---------------- ws layout (bytes) ----------------
#define OFF_WT     ((size_t)0)
#define OFF_GWT    ((size_t)131072)
#define OFF_GTOK   ((size_t)393216)
#define OFF_MASKS  ((size_t)655360)
#define OFF_COUNTS ((size_t)688128)
#define OFF_XB     ((size_t)1 << 20)
#define OFF_WGT    ((size_t)9 << 20)
#define OFF_WUT    ((size_t)73 << 20)
#define OFF_HBUF   ((size_t)137 << 20)

// ---------------- router: fp64 logits/scores (index-exactness vs np fp64 ref), top-8 ----------------
// NOTE: harness reads the whole d_out buffer as float32 and splits into chunks,
// so expert_index must be stored as FLOAT VALUES (0.0..63.0), not int32 bits.
__global__ __launch_bounds__(64) void router_kernel(
    const float* __restrict__ x, const float* __restrict__ wr,
    const float* __restrict__ bias,
    float* __restrict__ logits_out, float* __restrict__ idx_out,
    float* __restrict__ wt_buf, unsigned long long* __restrict__ masks,
    __bf16* __restrict__ xb)
{
    const int t = blockIdx.x;
    const int e = threadIdx.x;              // lane == expert
    const float4* x4 = (const float4*)(x + (size_t)t * H_DIM);
    const float4* w4 = (const float4*)(wr + (size_t)e * H_DIM);

    // fp64 accumulation: near-tie ordering must match the fp64 numpy reference
    double acc = 0.0;
    #pragma unroll 4
    for (int i = 0; i < H_DIM / 4; i++) {
        float4 a = x4[i], b = w4[i];
        acc += (double)a.x * (double)b.x + (double)a.y * (double)b.y
             + (double)a.z * (double)b.z + (double)a.w * (double)b.w;
    }
    logits_out[(size_t)t * E_EXP + e] = (float)acc;

    // cast my slice of x to bf16 (lane e covers float4 indices [4e, 4e+4))
    #pragma unroll
    for (int i2 = 0; i2 < 4; i2++) {
        float4 a = x4[e * 4 + i2];
        bf16x4 v;
        v[0] = (__bf16)a.x; v[1] = (__bf16)a.y; v[2] = (__bf16)a.z; v[3] = (__bf16)a.w;
        *(bf16x4*)(xb + (size_t)t * H_DIM + (size_t)(e * 4 + i2) * 4) = v;
    }

    const double aff = 1.0 / (1.0 + exp(-acc));   // unbiased affinity (used for weights)
    double cur = aff + (double)bias[e];           // biased selection score
    double myw = 0.0; int myi = 0;
    double wsum = 0.0;
    unsigned long long msk = 0ull;

    #pragma unroll
    for (int k = 0; k < KSEL; k++) {
        double rv = cur; int ri = e;
        // butterfly argmax, tie -> lower index (matches lax.top_k / stable descending sort)
        #pragma unroll
        for (int off = 32; off > 0; off >>= 1) {
            double ov = __shfl_xor(rv, off);
            int    oi = __shfl_xor(ri, off);
            if (ov > rv || (ov == rv && oi < ri)) { rv = ov; ri = oi; }
        }
        double wa = __shfl(aff, ri);
        wsum += wa;
        if (e == k)  { myi = ri; myw = wa; }
        if (e == ri) cur = -1e300;
        msk |= 1ull << ri;
    }
    if (e < KSEL) {
        idx_out[t * KSEL + e] = (float)myi;   // FLOAT value, see note above
        wt_buf[t * KSEL + e] = (float)(myw / wsum);
    }
    if (e == 0) masks[t] = msk;
}

// ---------------- scan: per-expert token-ordered gather lists ----------------
__global__ __launch_bounds__(64) void scan_kernel(
    const unsigned long long* __restrict__ masks,
    const float* __restrict__ idx_out, const float* __restrict__ wt_buf,
    int* __restrict__ gtok, float* __restrict__ gwt, int* __restrict__ counts)
{
    const int e = blockIdx.x;
    const int lane = threadIdx.x;
    int running = 0;
    for (int base = 0; base < T_TOK; base += 64) {
        const int t = base + lane;
        const int bit = (int)((masks[t] >> e) & 1ull);
        unsigned long long bal = __ballot(bit);
        int pre = __popcll(bal & ((1ull << lane) - 1ull));
        if (bit) {
            int pos = running + pre;
            if (pos < C_CAP) {   // capacity drop: later tokens dropped, matches cumsum order
                float w = 0.f;
                #pragma unroll
                for (int j = 0; j < KSEL; j++)
                    if ((int)idx_out[t * KSEL + j] == e) w = wt_buf[t * KSEL + j];
                gtok[e * C_CAP + pos] = t;
                gwt[e * C_CAP + pos] = w;
            }
        }
        running += __popcll(bal);
    }
    if (lane == 0) counts[e] = running < C_CAP ? running : C_CAP;
}

// ---------------- transpose + fp32->bf16 cast: in[e][R][Cc] -> out[e][Cc][R] ----------------
__global__ __launch_bounds__(256) void transpose_cast(
    const float* __restrict__ in, __bf16* __restrict__ out, int R, int Cc)
{
    const int e = blockIdx.z;
    const int r0 = blockIdx.y * 32;
    const int c0 = blockIdx.x * 32;
    __shared__ float tile[32][33];
    const int tid = threadIdx.x;
    const int tc = tid & 31, tr = tid >> 5;     // 32 cols x 8 rows per pass
    const float* src = in + ((size_t)e * R + r0) * Cc + c0;
    #pragma unroll
    for (int p = 0; p < 4; p++)
        tile[tr + p * 8][tc] = src[(size_t)(tr + p * 8) * Cc + tc];
    __syncthreads();
    __bf16* dst = out + ((size_t)e * Cc + c0) * R + r0;
    #pragma unroll
    for (int p = 0; p < 4; p++)
        dst[(size_t)(tr + p * 8) * R + tc] = (__bf16)tile[tc][tr + p * 8];
}

// ---------------- GEMM tile config ----------------
#define BM  128
#define BK  32
#define BN1 64      // per-output N tile for gate/up
#define BN2 128     // N tile for down
#define LDA 40      // padded LDS leading dim (bf16 elems); 80B row stride, 16B aligned
#define LDB 40

// gate+up fused: h[e][c][f] = silu(g)*u, A rows gathered from xb by token id
__global__ __launch_bounds__(256) void gemm_gateup(
    const __bf16* __restrict__ xb, const __bf16* __restrict__ wgT,
    const __bf16* __restrict__ wuT, const int* __restrict__ gtok,
    const int* __restrict__ counts, __bf16* __restrict__ hbuf)
{
    const int e = blockIdx.z;
    const int count = counts[e];
    const int m0 = blockIdx.y * BM;
    if (m0 >= count) return;
    const int n0 = blockIdx.x * BN1;

    __shared__ __bf16 As[BM * LDA];
    __shared__ __bf16 Bgs[BN1 * LDB];
    __shared__ __bf16 Bus[BN1 * LDB];

    const int tid  = threadIdx.x;
    const int lane = tid & 63;
    const int wave = tid >> 6;
    const int wm0 = (wave & 1) * 64;
    const int wn0 = (wave >> 1) * 32;
    const int q  = lane >> 4;
    const int ln = lane & 15;

    const int ra0 = tid >> 2, ra1 = ra0 + 64;
    const int ka  = (tid & 3) * 8;
    const int nb  = tid >> 2;
    const int kb  = (tid & 3) * 8;

    const int tok0 = (m0 + ra0 < count) ? gtok[e * C_CAP + m0 + ra0] : -1;
    const int tok1 = (m0 + ra1 < count) ? gtok[e * C_CAP + m0 + ra1] : -1;
    const __bf16* ap0 = xb + (size_t)(tok0 < 0 ? 0 : tok0) * H_DIM + ka;
    const __bf16* ap1 = xb + (size_t)(tok1 < 0 ? 0 : tok1) * H_DIM + ka;
    const __bf16* gp = wgT + ((size_t)e * F_DIM + n0 + nb) * H_DIM + kb;
    const __bf16* up = wuT + ((size_t)e * F_DIM + n0 + nb) * H_DIM + kb;

    bf16x8 zero;
    #pragma unroll
    for (int i = 0; i < 8; i++) zero[i] = (__bf16)0.f;

    bf16x8 va0 = (tok0 >= 0) ? *(const bf16x8*)ap0 : zero;
    bf16x8 va1 = (tok1 >= 0) ? *(const bf16x8*)ap1 : zero;
    bf16x8 vg  = *(const bf16x8*)gp;
    bf16x8 vu  = *(const bf16x8*)up;

    f32x4 accg[4][2] = {};
    f32x4 accu[4][2] = {};

    for (int k0 = 0; k0 < H_DIM; k0 += BK) {
        __syncthreads();
        *(bf16x8*)(&As[ra0 * LDA + ka]) = va0;
        *(bf16x8*)(&As[ra1 * LDA + ka]) = va1;
        *(bf16x8*)(&Bgs[nb * LDB + kb]) = vg;
        *(bf16x8*)(&Bus[nb * LDB + kb]) = vu;
        __syncthreads();
        const int kn = k0 + BK;
        if (kn < H_DIM) {   // prefetch next staging into VGPRs, overlaps MFMA
            va0 = (tok0 >= 0) ? *(const bf16x8*)(ap0 + kn) : zero;
            va1 = (tok1 >= 0) ? *(const bf16x8*)(ap1 + kn) : zero;
            vg  = *(const bf16x8*)(gp + kn);
            vu  = *(const bf16x8*)(up + kn);
        }
        bf16x8 af[4], bg[2], bu[2];
        #pragma unroll
        for (int i = 0; i < 4; i++)
            af[i] = *(const bf16x8*)(&As[(wm0 + i * 16 + ln) * LDA + q * 8]);
        #pragma unroll
        for (int j = 0; j < 2; j++) {
            bg[j] = *(const bf16x8*)(&Bgs[(wn0 + j * 16 + ln) * LDB + q * 8]);
            bu[j] = *(const bf16x8*)(&Bus[(wn0 + j * 16 + ln) * LDB + q * 8]);
        }
        #pragma unroll
        for (int i = 0; i < 4; i++)
            #pragma unroll
            for (int j = 0; j < 2; j++) {
                accg[i][j] = __builtin_amdgcn_mfma_f32_16x16x32_bf16(af[i], bg[j], accg[i][j], 0, 0, 0);
                accu[i][j] = __builtin_amdgcn_mfma_f32_16x16x32_bf16(af[i], bu[j], accu[i][j], 0, 0, 0);
            }
    }

    // epilogue: h = silu(g) * u -> bf16 (zero rows beyond count come out 0, harmless)
    #pragma unroll
    for (int i = 0; i < 4; i++) {
        const int mb = m0 + wm0 + i * 16 + q * 4;
        #pragma unroll
        for (int j = 0; j < 2; j++) {
            const int fc = n0 + wn0 + j * 16 + ln;
            #pragma unroll
            for (int r = 0; r < 4; r++) {
                float g = accg[i][j][r];
                float u = accu[i][j][r];
                float s = g / (1.f + __expf(-g));
                hbuf[((size_t)e * C_CAP + (mb + r)) * F_DIM + fc] = (__bf16)(s * u);
            }
        }
    }
}

// down GEMM + weighted scatter-combine into y (fp32 atomics; 8 adds/elem, no conflicts in practice)
__global__ __launch_bounds__(256) void gemm_down(
    const __bf16* __restrict__ hbuf, const __bf16* __restrict__ wdT,
    const int* __restrict__ gtok, const float* __restrict__ gwt,
    const int* __restrict__ counts, float* __restrict__ y)
{
    const int e = blockIdx.z;
    const int count = counts[e];
    const int m0 = blockIdx.y * BM;
    if (m0 >= count) return;
    const int n0 = blockIdx.x * BN2;

    __shared__ __bf16 As[BM * LDA];
    __shared__ __bf16 Bs[BN2 * LDB];

    const int tid  = threadIdx.x;
    const int lane = tid & 63;
    const int wave = tid >> 6;
    const int wm0 = (wave & 1) * 64;
    const int wn0 = (wave >> 1) * 64;
    const int q  = lane >> 4;
    const int ln = lane & 15;

    const int ra0 = tid >> 2, ra1 = ra0 + 64;
    const int ka  = (tid & 3) * 8;
    const int nb0 = tid >> 2, nb1 = nb0 + 64;
    const int kb  = (tid & 3) * 8;

    const __bf16* ap0 = hbuf + ((size_t)e * C_CAP + m0 + ra0) * F_DIM + ka;
    const __bf16* ap1 = hbuf + ((size_t)e * C_CAP + m0 + ra1) * F_DIM + ka;
    const __bf16* bp0 = wdT + ((size_t)e * H_DIM + n0 + nb0) * F_DIM + kb;
    const __bf16* bp1 = wdT + ((size_t)e * H_DIM + n0 + nb1) * F_DIM + kb;

    bf16x8 va0 = *(const bf16x8*)ap0;
    bf16x8 va1 = *(const bf16x8*)ap1;
    bf16x8 vb0 = *(const bf16x8*)bp0;
    bf16x8 vb1 = *(const bf16x8*)bp1;

    f32x4 acc[4][4] = {};

    for (int k0 = 0; k0 < F_DIM; k0 += BK) {
        __syncthreads();
        *(bf16x8*)(&As[ra0 * LDA + ka]) = va0;
        *(bf16x8*)(&As[ra1 * LDA + ka]) = va1;
        *(bf16x8*)(&Bs[nb0 * LDB + kb]) = vb0;
        *(bf16x8*)(&Bs[nb1 * LDB + kb]) = vb1;
        __syncthreads();
        const int kn = k0 + BK;
        if (kn < F_DIM) {
            va0 = *(const bf16x8*)(ap0 + kn);
            va1 = *(const bf16x8*)(ap1 + kn);
            vb0 = *(const bf16x8*)(bp0 + kn);
            vb1 = *(const bf16x8*)(bp1 + kn);
        }
        bf16x8 af[4], bb[4];
        #pragma unroll
        for (int i = 0; i < 4; i++)
            af[i] = *(const bf16x8*)(&As[(wm0 + i * 16 + ln) * LDA + q * 8]);
        #pragma unroll
        for (int j = 0; j < 4; j++)
            bb[j] = *(const bf16x8*)(&Bs[(wn0 + j * 16 + ln) * LDB + q * 8]);
        #pragma unroll
        for (int i = 0; i < 4; i++)
            #pragma unroll
            for (int j = 0; j < 4; j++)
                acc[i][j] = __builtin_amdgcn_mfma_f32_16x16x32_bf16(af[i], bb[j], acc[i][j], 0, 0, 0);
    }

    #pragma unroll
    for (int i = 0; i < 4; i++) {
        const int mb = wm0 + i * 16 + q * 4;
        int tokr[4]; float wtr[4];
        #pragma unroll
        for (int r = 0; r < 4; r++) {
            const int row = m0 + mb + r;
            const bool v = row < count;
            tokr[r] = v ? gtok[e * C_CAP + row] : -1;
            wtr[r]  = v ? gwt[e * C_CAP + row] : 0.f;
        }
        #pragma unroll
        for (int j = 0; j < 4; j++) {
            const int hc = n0 + wn0 + j * 16 + ln;
            #pragma unroll
            for (int r = 0; r < 4; r++) {
                if (tokr[r] >= 0)
                    atomicAdd(&y[(size_t)tokr[r] * H_DIM + hc], acc[i][j][r] * wtr[r]);
            }
        }
    }
}

extern "C" void kernel_launch(void* const* d_in, const int* in_sizes, int n_in,
                              void* d_out, int out_size, void* d_ws, size_t ws_size,
                              hipStream_t stream)
{
    const float* x    = (const float*)d_in[0];
    const float* wr   = (const float*)d_in[1];
    const float* bias = (const float*)d_in[2];
    const float* wg   = (const float*)d_in[3];
    const float* wu   = (const float*)d_in[4];
    const float* wd   = (const float*)d_in[5];

    float* y      = (float*)d_out;
    float* logits = y + (size_t)T_TOK * H_DIM;
    float* idxo   = logits + (size_t)T_TOK * E_EXP;   // stored as float values (harness reads f32)

    char* ws = (char*)d_ws;
    float*  wt_buf = (float*)(ws + OFF_WT);
    float*  gwt    = (float*)(ws + OFF_GWT);
    int*    gtok   = (int*)(ws + OFF_GTOK);
    unsigned long long* masks = (unsigned long long*)(ws + OFF_MASKS);
    int*    counts = (int*)(ws + OFF_COUNTS);
    __bf16* xb   = (__bf16*)(ws + OFF_XB);
    __bf16* wgT  = (__bf16*)(ws + OFF_WGT);
    __bf16* wuT  = (__bf16*)(ws + OFF_WUT);
    __bf16* wdT  = wuT;                       // w_down transposed reuses w_up region after gemm1
    __bf16* hbuf = (__bf16*)(ws + OFF_HBUF);

    // y accumulated by atomics -> zero it (harness poisons d_out each call)
    hipMemsetAsync(d_out, 0, (size_t)T_TOK * H_DIM * sizeof(float), stream);

    router_kernel<<<T_TOK, 64, 0, stream>>>(x, wr, bias, logits, idxo, wt_buf, masks, xb);
    scan_kernel<<<E_EXP, 64, 0, stream>>>(masks, idxo, wt_buf, gtok, gwt, counts);

    // w_gate/w_up: [E][H][F] -> [E][F][H]
    transpose_cast<<<dim3(F_DIM / 32, H_DIM / 32, E_EXP), 256, 0, stream>>>(wg, wgT, H_DIM, F_DIM);
    transpose_cast<<<dim3(F_DIM / 32, H_DIM / 32, E_EXP), 256, 0, stream>>>(wu, wuT, H_DIM, F_DIM);

    gemm_gateup<<<dim3(F_DIM / BN1, C_CAP / BM, E_EXP), 256, 0, stream>>>(
        xb, wgT, wuT, gtok, counts, hbuf);

    // w_down: [E][F][H] -> [E][H][F], into wuT region (dead after gemm_gateup)
    transpose_cast<<<dim3(H_DIM / 32, F_DIM / 32, E_EXP), 256, 0, stream>>>(wd, wdT, F_DIM, H_DIM);

    gemm_down<<<dim3(H_DIM / BN2, C_CAP / BM, E_EXP), 256, 0, stream>>>(
        hbuf, wdT, gtok, gwt, counts, y);
}